// Round 6
// baseline (224.933 us; speedup 1.0000x reference)
//
#include <hip/hip_runtime.h>

#define TSEQ 512
#define NB   128
#define CDIM 384
#define HD   64
#define QSCALE 0.051031036307982884f   // 384^-0.5, folded into Q at projection
#define MBIAS  8.0f                    // fixed softmax offset (exact: cancels in O=PV/l)

typedef _Float16 half8  __attribute__((ext_vector_type(8)));
typedef _Float16 half4  __attribute__((ext_vector_type(4)));
typedef float    floatx4 __attribute__((ext_vector_type(4)));

typedef __attribute__((address_space(3))) unsigned int lds_u32;
typedef const __attribute__((address_space(1))) unsigned int g_u32;

__device__ __forceinline__ void load_lds16(const void* g, void* l) {
    // async global->LDS DMA, 16B/lane; LDS dst = wave-uniform base + lane*16
    __builtin_amdgcn_global_load_lds((g_u32*)g, (lds_u32*)l, 16, 0, 0);
}

// ---------------------------------------------------------------------------
// Kernel B: pack the three 384x64 fp32 weights into the EXACT LDS staging
// order (12 chunks of BK=32):
//   Wp[c][kblk(4)][n(192)][kin(8)] = w_mat(n/64)[(c*32 + kblk*8 + kin)*64 + n%64]
// so qkv W staging is fully-contiguous 1-KB global_load_lds (linear copy).
// ---------------------------------------------------------------------------
__global__ void prep_w(const float* __restrict__ wq, const float* __restrict__ wk,
                       const float* __restrict__ wv, _Float16* __restrict__ Wp)
{
    int i = blockIdx.x * 256 + threadIdx.x;
    if (i >= 3 * CDIM * HD) return;                 // 73728
    int c    = i / 6144;  int r  = i - c * 6144;    // chunk (BK=32)
    int kblk = r / 1536;  int r2 = r - kblk * 1536;
    int n    = r2 >> 3;   int kin = r2 & 7;
    int k    = c * 32 + kblk * 8 + kin;
    int mat  = n / 64;    int col = n - mat * 64;
    const float* w = (mat == 0) ? wq : ((mat == 1) ? wk : wv);
    Wp[i] = (_Float16)w[k * HD + col];
}

// ---------------------------------------------------------------------------
// Kernel C: fused QKV projection -- X-IN-FLIGHT round.
// Diagnosis (r0-r5): every prior variant capped the x stream's outstanding
// bytes (barrier-drained DMA, or 2-deep register prefetch = 32 B/wave);
// x = 2/3 of traffic, HBM-cold each iteration (403-MB poison flushes L3)
// -> 0.3-1.2 TB/s effective, ~60 us. Fix: stage the block's ENTIRE x tile
// (32 rows x 384 = 48 KB) into LDS with 24 back-to-back global_load_lds
// per wave at kernel start -> 24 KB in flight PER WAVE, never drained:
// per-chunk wait is vmcnt(2*(11-c)+6), which only requires X(<=c), W(<=c).
// W: double-buffered (24 KB), 6 DMAs/wave/chunk, issued one chunk ahead.
// Two barriers per chunk: wait-barrier (all waves' W(c),X(c) visible) and
// reuse-barrier (protects W buffer c-1 before stage c+1 overwrites it).
// Geometry: 2048 blocks of 32 rows, 2 waves (wave = 16 rows x 192 cols,
// acc[12]); LDS 72 KB -> 2 blocks/CU so block n+1's DMA burst overlaps
// block n's compute tail.
// x swizzle: DMA dest is linear (HW constraint), so the SOURCE 16-B unit
// is XOR'd per row (u ^ (m&7)) and the A-read applies the same XOR ->
// 2-way bank alias only (free).
// Epilogue: bias + RoPE (fres==1 -> angle=t) via shfl_xor 1; Q scaled.
// Q,K (b,t,d) fp16; V transposed (b,d,t) fp16.
// ---------------------------------------------------------------------------
__global__ __launch_bounds__(128) void qkv_gemm(
    const float* __restrict__ x, const _Float16* __restrict__ Wp,
    const float* __restrict__ bq, const float* __restrict__ bk,
    const float* __restrict__ bv,
    _Float16* __restrict__ Qw, _Float16* __restrict__ Kw,
    _Float16* __restrict__ Vtw, int b0)
{
    __shared__ __align__(16) float    xs[12 * 32 * 32];  // 48 KB [c][m(32)][32k]
    __shared__ __align__(16) _Float16 wsb[2][6144];      // 24 KB, double buffer

    const int tid  = threadIdx.x;
    const int wave = tid >> 6;                           // 0..1
    const int lane = tid & 63;
    const int l16  = lane & 15;
    const int quad = lane >> 4;

    const int row0 = blockIdx.x * 32;                    // chunk-local row base
    const size_t rowg = (size_t)b0 * TSEQ + row0;        // global row base

    // ---- per-lane X staging source/dest (constant across chunks) ----
    const float* xsrc[2];
    int xdst[2];
#pragma unroll
    for (int i = 0; i < 2; ++i) {
        const int t0 = (wave * 2 + i) * 64;              // base 16B-unit of inst
        const int t  = t0 + lane;                        // this lane's unit
        const int m  = t >> 3;                           // row 0..31
        const int u  = t & 7;                            // unit-in-row 0..7
        const int usw = u ^ (m & 7);                     // source swizzle
        xsrc[i] = x + (rowg + m) * CDIM + usw * 4;
        xdst[i] = t0 * 16;                               // byte offset in xs
    }
    int woff[6];
#pragma unroll
    for (int i = 0; i < 6; ++i) woff[i] = (wave * 6 + i) * 512 + lane * 8;

    floatx4 acc[12];
#pragma unroll
    for (int i = 0; i < 12; ++i)
#pragma unroll
        for (int r = 0; r < 4; ++r) acc[i][r] = 0.f;

    // ---- issue the ENTIRE x tile: 24 DMAs/wave, ordered by chunk ----
#pragma unroll
    for (int c = 0; c < 12; ++c)
#pragma unroll
        for (int i = 0; i < 2; ++i)
            load_lds16(xsrc[i] + c * 32, (char*)xs + c * 4096 + xdst[i]);

#define WSTAGE(cc) do { _Pragma("unroll")                                     \
    for (int i_ = 0; i_ < 6; ++i_)                                            \
        load_lds16(Wp + (size_t)(cc) * 6144 + woff[i_],                       \
                   (char*)&wsb[(cc) & 1][0] + (wave * 6 + i_) * 1024);        \
} while (0)

#define CHUNK(cc, VM) do {                                                    \
    if ((cc) + 1 < 12) WSTAGE((cc) + 1);                                      \
    asm volatile("s_waitcnt vmcnt(" VM ")" ::: "memory");                     \
    __builtin_amdgcn_s_barrier();      /* all waves' X(c),W(c) now visible */ \
    const int m_  = wave * 16 + l16;                                          \
    const int mh_ = m_ & 7;                                                   \
    const float* ap = xs + (cc) * 1024 + m_ * 32;                             \
    floatx4 a0 = *(const floatx4*)(ap + (((quad * 2)     ^ mh_) << 2));       \
    floatx4 a1 = *(const floatx4*)(ap + (((quad * 2 + 1) ^ mh_) << 2));       \
    half8 aF;                                                                 \
    _Pragma("unroll")                                                         \
    for (int jj = 0; jj < 8; ++jj)                                            \
        aF[jj] = (_Float16)(jj < 4 ? a0[jj] : a1[jj - 4]);                    \
    const _Float16* bp = &wsb[(cc) & 1][0] + ((size_t)quad * 192 + l16) * 8;  \
    _Pragma("unroll")                                                         \
    for (int i_ = 0; i_ < 12; ++i_) {                                         \
        half8 bb = *(const half8*)(bp + i_ * 128);                            \
        acc[i_] = __builtin_amdgcn_mfma_f32_16x16x32_f16(aF, bb, acc[i_], 0, 0, 0); \
    }                                                                         \
    __builtin_amdgcn_s_barrier();      /* W buffer (cc-1) safe to overwrite */\
} while (0)

    WSTAGE(0);
    // outstanding at wait(c) = X(chunks>c): 2*(11-c)  +  W(c+1): 6
    CHUNK(0,  "28");  CHUNK(1,  "26");  CHUNK(2,  "24");  CHUNK(3,  "22");
    CHUNK(4,  "20");  CHUNK(5,  "18");  CHUNK(6,  "16");  CHUNK(7,  "14");
    CHUNK(8,  "12");  CHUNK(9,  "10");  CHUNK(10, "8");   CHUNK(11, "0");

#undef CHUNK
#undef WSTAGE

    // ---- epilogue: bias + RoPE; Q/K row-major, V transposed (b,d,t) ----
    float bq4[4], bk4[4], bv4[4];
#pragma unroll
    for (int s4 = 0; s4 < 4; ++s4) {
        const int cc = s4 * 16 + l16;
        bq4[s4] = bq[cc]; bk4[s4] = bk[cc]; bv4[s4] = bv[cc];
    }
    const int bidx = row0 >> 9;                          // chunk-local batch
    const int t00  = (row0 & (TSEQ - 1)) + wave * 16 + quad * 4;
    const int rowb = row0 + wave * 16 + quad * 4;

#pragma unroll
    for (int r = 0; r < 4; ++r) {
        const int t = t00 + r;
        const float st = sinf((float)t);
        const float ct = cosf((float)t);
        const int row = rowb + r;
#pragma unroll
        for (int s4 = 0; s4 < 4; ++s4) {
            const int cc = s4 * 16 + l16;
            float vq = acc[s4][r] + bq4[s4];
            float pq = __shfl_xor(vq, 1);
            vq = (cc & 1) ? (pq * st + vq * ct) : (vq * ct - pq * st);
            Qw[(size_t)row * HD + cc] = (_Float16)(vq * QSCALE);
            float vk = acc[4 + s4][r] + bk4[s4];
            float pk = __shfl_xor(vk, 1);
            vk = (cc & 1) ? (pk * st + vk * ct) : (vk * ct - pk * st);
            Kw[(size_t)row * HD + cc] = (_Float16)vk;
        }
    }
    // V: pack 4 consecutive t per store (t = t00..t00+3 contiguous)
#pragma unroll
    for (int s4 = 0; s4 < 4; ++s4) {
        const int cc = s4 * 16 + l16;
        half4 vpack;
#pragma unroll
        for (int r = 0; r < 4; ++r) vpack[r] = (_Float16)(acc[8 + s4][r] + bv4[s4]);
        *(half4*)(Vtw + ((size_t)bidx * HD + cc) * TSEQ + t00) = vpack;
    }
}

// ---------------------------------------------------------------------------
// Kernel D: causal flash attention (UNCHANGED from round 4 -- single-variable
// attribution). Grid (16, nb); each block owns ONE balanced strip pair
// (pr, 31-pr) = 9 tile-units; its 4 waves split the k-range by j mod 4 and
// merge through LDS at the end (exact: fixed-bias softmax -> partials
// additive). V loaded after K dies (-32 live VGPR). XCD swizzle keeps a
// batch's 16 blocks on one XCD.
// ---------------------------------------------------------------------------
__global__ __launch_bounds__(256, 3) void attn_kernel(
    const _Float16* __restrict__ Qw, const _Float16* __restrict__ Kw,
    const _Float16* __restrict__ Vtw, float* __restrict__ out, int b0)
{
    int bx, bl;
    {
        const int lin = blockIdx.y * 16 + blockIdx.x;
        if ((gridDim.y & 7) == 0) {                  // bijective XCD grouping
            const int per = gridDim.y >> 3;          // batches per XCD
            const int xcd = lin & 7;
            const int k2  = lin >> 3;                // [0, 2*nb)
            bl = xcd * per + (k2 >> 4);
            bx = k2 & 15;
        } else { bx = blockIdx.x; bl = blockIdx.y; }
    }
    const int tid  = threadIdx.x;
    const int wave = tid >> 6;
    const int lane = tid & 63;
    const int l16  = lane & 15;
    const int quad = lane >> 4;

    const int pr  = bx;                              // strip pair 0..15
    const int h   = wave;                            // k-phase (j mod 4)
    const int qA  = pr * 16;                         // near strip rows
    const int qB  = (31 - pr) * 16;                  // far strip rows
    const int jdA = pr >> 2;                         // diag tile, strip A
    const int jdB = (31 - pr) >> 2;                  // diag tile, strip B

    __shared__ __align__(16) _Float16 pbuf[4][16][72];
    __shared__ __align__(16) floatx4  mbuf[3][10][64];   // merge buffer

    const _Float16* Qb = Qw  + (size_t)bl * TSEQ * HD;
    const _Float16* Kb = Kw  + (size_t)bl * TSEQ * HD;
    const _Float16* Vb = Vtw + (size_t)bl * HD * TSEQ;   // [d][t]

    half8 aQA0 = *(const half8*)(Qb + (size_t)(qA + l16) * HD + quad * 8);
    half8 aQA1 = *(const half8*)(Qb + (size_t)(qA + l16) * HD + 32 + quad * 8);
    half8 aQB0 = *(const half8*)(Qb + (size_t)(qB + l16) * HD + quad * 8);
    half8 aQB1 = *(const half8*)(Qb + (size_t)(qB + l16) * HD + 32 + quad * 8);

    half8 ones;
#pragma unroll
    for (int jj = 0; jj < 8; ++jj) ones[jj] = (_Float16)1.f;

    floatx4 accO[8], accL[2];
#pragma unroll
    for (int i = 0; i < 8; ++i)
#pragma unroll
        for (int r = 0; r < 4; ++r) accO[i][r] = 0.f;
#pragma unroll
    for (int s = 0; s < 2; ++s)
#pragma unroll
        for (int r = 0; r < 4; ++r) accL[s][r] = 0.f;

    for (int j = h; j <= jdB; j += 4) {
        const int kb = j * 64;
        const bool actA = (j <= jdA);

        // ---- K fragments (shared by both strips; dead before V loads) ----
        half8 bK0[4], bK1[4];
#pragma unroll
        for (int s4 = 0; s4 < 4; ++s4) {
            const _Float16* kp = Kb + (size_t)(kb + s4 * 16 + l16) * HD + quad * 8;
            bK0[s4] = *(const half8*)(kp);
            bK1[s4] = *(const half8*)(kp + 32);
        }

        // ---- strip A: QK^T + exp -> pbuf (st4A dies before B's QK) ----
        if (actA) {
            floatx4 st4[4];
            __builtin_amdgcn_s_setprio(1);
#pragma unroll
            for (int s4 = 0; s4 < 4; ++s4) {
#pragma unroll
                for (int r = 0; r < 4; ++r) st4[s4][r] = 0.f;
                st4[s4] = __builtin_amdgcn_mfma_f32_16x16x32_f16(bK0[s4], aQA0, st4[s4], 0, 0, 0);
                st4[s4] = __builtin_amdgcn_mfma_f32_16x16x32_f16(bK1[s4], aQA1, st4[s4], 0, 0, 0);
            }
            __builtin_amdgcn_s_setprio(0);
            const int qrow = qA + l16;
#pragma unroll
            for (int s4 = 0; s4 < 4; ++s4) {
                half4 w;
#pragma unroll
                for (int r = 0; r < 4; ++r) {
                    float p = __expf(fminf(st4[s4][r], 18.f) - MBIAS);
                    if (j == jdA) {
                        const int kcol = kb + s4 * 16 + quad * 4 + r;
                        if (kcol > qrow) p = 0.f;
                    }
                    w[r] = (_Float16)p;
                }
                *(half4*)(&pbuf[wave][l16][s4 * 16 + quad * 4]) = w;
            }
        }

        // ---- strip B: QK^T (K dies here) ----
        floatx4 stB[4];
        __builtin_amdgcn_s_setprio(1);
#pragma unroll
        for (int s4 = 0; s4 < 4; ++s4) {
#pragma unroll
            for (int r = 0; r < 4; ++r) stB[s4][r] = 0.f;
            stB[s4] = __builtin_amdgcn_mfma_f32_16x16x32_f16(bK0[s4], aQB0, stB[s4], 0, 0, 0);
            stB[s4] = __builtin_amdgcn_mfma_f32_16x16x32_f16(bK1[s4], aQB1, stB[s4], 0, 0, 0);
        }
        __builtin_amdgcn_s_setprio(0);

        // ---- V fragments (allocator reuses K's registers) ----
        half8 bV0[4], bV1[4];
#pragma unroll
        for (int s4 = 0; s4 < 4; ++s4) {
            const _Float16* vp = Vb + (size_t)(s4 * 16 + l16) * TSEQ + kb + quad * 8;
            bV0[s4] = *(const half8*)(vp);
            bV1[s4] = *(const half8*)(vp + 32);
        }

        // ---- strip A: PV (pbuf read precedes B's pbuf overwrite) ----
        if (actA) {
            half8 aP0 = *(const half8*)(&pbuf[wave][l16][quad * 8]);
            half8 aP1 = *(const half8*)(&pbuf[wave][l16][32 + quad * 8]);
            __builtin_amdgcn_s_setprio(1);
#pragma unroll
            for (int s4 = 0; s4 < 4; ++s4) {
                accO[s4] = __builtin_amdgcn_mfma_f32_16x16x32_f16(aP0, bV0[s4], accO[s4], 0, 0, 0);
                accO[s4] = __builtin_amdgcn_mfma_f32_16x16x32_f16(aP1, bV1[s4], accO[s4], 0, 0, 0);
            }
            accL[0] = __builtin_amdgcn_mfma_f32_16x16x32_f16(aP0, ones, accL[0], 0, 0, 0);
            accL[0] = __builtin_amdgcn_mfma_f32_16x16x32_f16(aP1, ones, accL[0], 0, 0, 0);
            __builtin_amdgcn_s_setprio(0);
        }

        // ---- strip B: exp -> pbuf, PV ----
        {
            const int qrow = qB + l16;
#pragma unroll
            for (int s4 = 0; s4 < 4; ++s4) {
                half4 w;
#pragma unroll
                for (int r = 0; r < 4; ++r) {
                    float p = __expf(fminf(stB[s4][r], 18.f) - MBIAS);
                    if (j == jdB) {
                        const int kcol = kb + s4 * 16 + quad * 4 + r;
                        if (kcol > qrow) p = 0.f;
                    }
                    w[r] = (_Float16)p;
                }
                *(half4*)(&pbuf[wave][l16][s4 * 16 + quad * 4]) = w;
            }
            half8 aP0 = *(const half8*)(&pbuf[wave][l16][quad * 8]);
            half8 aP1 = *(const half8*)(&pbuf[wave][l16][32 + quad * 8]);
            __builtin_amdgcn_s_setprio(1);
#pragma unroll
            for (int s4 = 0; s4 < 4; ++s4) {
                accO[4 + s4] = __builtin_amdgcn_mfma_f32_16x16x32_f16(aP0, bV0[s4], accO[4 + s4], 0, 0, 0);
                accO[4 + s4] = __builtin_amdgcn_mfma_f32_16x16x32_f16(aP1, bV1[s4], accO[4 + s4], 0, 0, 0);
            }
            accL[1] = __builtin_amdgcn_mfma_f32_16x16x32_f16(aP0, ones, accL[1], 0, 0, 0);
            accL[1] = __builtin_amdgcn_mfma_f32_16x16x32_f16(aP1, ones, accL[1], 0, 0, 0);
            __builtin_amdgcn_s_setprio(0);
        }
    }

    // ---- merge the 4 k-phases (exact: fixed-bias softmax) ----
    if (h != 0) {
#pragma unroll
        for (int i = 0; i < 8; ++i) mbuf[h - 1][i][lane] = accO[i];
        mbuf[h - 1][8][lane] = accL[0];
        mbuf[h - 1][9][lane] = accL[1];
    }
    __syncthreads();
    if (h != 0) return;

#pragma unroll
    for (int m = 0; m < 3; ++m) {
#pragma unroll
        for (int i = 0; i < 8; ++i) {
            floatx4 t = mbuf[m][i][lane];
#pragma unroll
            for (int r = 0; r < 4; ++r) accO[i][r] += t[r];
        }
        floatx4 t8 = mbuf[m][8][lane];
        floatx4 t9 = mbuf[m][9][lane];
#pragma unroll
        for (int r = 0; r < 4; ++r) { accL[0][r] += t8[r]; accL[1][r] += t9[r]; }
    }

    // ---- epilogue (phase-0 wave writes both strips) ----
#pragma unroll
    for (int s = 0; s < 2; ++s) {
        const int qbase = (s == 0) ? qA : qB;
        float inv[4];
#pragma unroll
        for (int r = 0; r < 4; ++r) inv[r] = 1.f / accL[s][r];
#pragma unroll
        for (int s4 = 0; s4 < 4; ++s4) {
            const int dcol = s4 * 16 + l16;
#pragma unroll
            for (int r = 0; r < 4; ++r) {
                const int qr = qbase + quad * 4 + r;
                out[((size_t)(b0 + bl) * TSEQ + qr) * HD + dcol] =
                    accO[s * 4 + s4][r] * inv[r];
            }
        }
    }
}

// ---------------------------------------------------------------------------
extern "C" void kernel_launch(void* const* d_in, const int* in_sizes, int n_in,
                              void* d_out, int out_size, void* d_ws, size_t ws_size,
                              hipStream_t stream)
{
    char* ws = (char*)d_ws;
    _Float16* Wp = (_Float16*)ws;                           // 147456 B
    char* qkv_base = ws + 147456;

    const size_t per_b = (size_t)3 * TSEQ * HD * sizeof(_Float16);  // 196608 B
    size_t avail = (ws_size > (size_t)147456) ? ws_size - 147456 : per_b;
    int nbc = (int)(avail / per_b);
    if (nbc > NB) nbc = NB;
    if (nbc < 1)  nbc = 1;

    const size_t chunk_elems = (size_t)nbc * TSEQ * HD;
    _Float16* Qw  = (_Float16*)qkv_base;
    _Float16* Kw  = Qw + chunk_elems;
    _Float16* Vtw = Kw + chunk_elems;

    prep_w<<<dim3((3 * CDIM * HD + 255) / 256), dim3(256), 0, stream>>>(
        (const float*)d_in[1], (const float*)d_in[3], (const float*)d_in[5], Wp);

    for (int b0 = 0; b0 < NB; b0 += nbc) {
        const int nb = (NB - b0 < nbc) ? (NB - b0) : nbc;
        qkv_gemm<<<dim3(nb * 16), dim3(128), 0, stream>>>(
            (const float*)d_in[0], Wp, (const float*)d_in[2], (const float*)d_in[4],
            (const float*)d_in[6], Qw, Kw, Vtw, b0);
        attn_kernel<<<dim3(16, nb), dim3(256), 0, stream>>>(
            Qw, Kw, Vtw, (float*)d_out, b0);
    }
}

// Round 7
// 221.446 us; speedup vs baseline: 1.0157x; 1.0157x over previous
//
#include <hip/hip_runtime.h>

#define TSEQ 512
#define NB   128
#define CDIM 384
#define HD   64
#define QSCALE 0.051031036307982884f   // 384^-0.5, folded into Q at projection
#define MBIAS  8.0f                    // fixed softmax offset (exact: cancels in O=PV/l)

typedef _Float16 half8  __attribute__((ext_vector_type(8)));
typedef _Float16 half4  __attribute__((ext_vector_type(4)));
typedef float    floatx4 __attribute__((ext_vector_type(4)));

typedef __attribute__((address_space(3))) unsigned int lds_u32;
typedef const __attribute__((address_space(1))) unsigned int g_u32;

__device__ __forceinline__ void load_lds16(const void* g, void* l) {
    // async global->LDS DMA, 16B/lane; LDS dst = wave-uniform base + lane*16
    __builtin_amdgcn_global_load_lds((g_u32*)g, (lds_u32*)l, 16, 0, 0);
}

// ---------------------------------------------------------------------------
// Kernel B: pack the three 384x64 fp32 weights into the EXACT LDS staging
// order (12 chunks of BK=32):
//   Wp[c][kblk(4)][n(192)][kin(8)] = w_mat(n/64)[(c*32 + kblk*8 + kin)*64 + n%64]
// so qkv W staging is fully-contiguous 1-KB global_load_lds (linear copy).
// ---------------------------------------------------------------------------
__global__ void prep_w(const float* __restrict__ wq, const float* __restrict__ wk,
                       const float* __restrict__ wv, _Float16* __restrict__ Wp)
{
    int i = blockIdx.x * 256 + threadIdx.x;
    if (i >= 3 * CDIM * HD) return;                 // 73728
    int c    = i / 6144;  int r  = i - c * 6144;    // chunk (BK=32)
    int kblk = r / 1536;  int r2 = r - kblk * 1536;
    int n    = r2 >> 3;   int kin = r2 & 7;
    int k    = c * 32 + kblk * 8 + kin;
    int mat  = n / 64;    int col = n - mat * 64;
    const float* w = (mat == 0) ? wq : ((mat == 1) ? wk : wv);
    Wp[i] = (_Float16)w[k * HD + col];
}

// ---------------------------------------------------------------------------
// Kernel C: fused QKV projection -- DEEP-X round. r5 skeleton (entire 144-KiB
// packed W resident in LDS, staged once; K-loop has ZERO barriers and zero
// inter-wave coupling) with ONE change: the x register stream is prefetched
// FIVE chunks deep (6 rotating statically-named slots) instead of two.
// Ledger says register per-lane loads are the fast path (r5: 1.71 TB/s vs
// 1.06-1.3 for DMA-heavy variants; m13's 6.3 TB/s copy is register loads)
// and r5's residual cap was outstanding bytes (2 chunks = 8 KB/wave).
// Now ~20 KB/wave (~160 KB/CU) stays in flight.
// Prologue ordering fix (r6 lesson): W DMAs issued FIRST (18/wave), then the
// 5 x-chunk loads; raw s_barrier + vmcnt(20) completes exactly the 18 W DMAs
// while keeping all 20 x loads outstanding (no __syncthreads vmcnt(0) drain).
// Geometry: 256 blocks x 512 threads (1 block/CU: LDS-capped), wave owns
// 32 rows as 2x16-row groups sharing every B ds_read (acc[2][12]).
// Epilogue: bias + RoPE (fres==1 -> angle=t) via shfl_xor 1; Q scaled.
// Q,K (b,t,d) fp16; V transposed (b,d,t) fp16.
// ---------------------------------------------------------------------------
__global__ __launch_bounds__(512) void qkv_gemm(
    const float* __restrict__ x, const _Float16* __restrict__ Wp,
    const float* __restrict__ bq, const float* __restrict__ bk,
    const float* __restrict__ bv,
    _Float16* __restrict__ Qw, _Float16* __restrict__ Kw,
    _Float16* __restrict__ Vtw, int b0)
{
    __shared__ __align__(16) _Float16 wsb[12][6144];     // 144 KiB, resident W

    const int tid  = threadIdx.x;
    const int wave = tid >> 6;                           // 0..7
    const int lane = tid & 63;
    const int l16  = lane & 15;
    const int quad = lane >> 4;

    const int row0 = blockIdx.x * 256;                   // chunk-local row base
    const size_t rowg = (size_t)b0 * TSEQ + row0;        // global row base

    // ---- stage ALL of W: 144 linear 1-KB DMAs, 18 per wave (issued FIRST) --
#pragma unroll
    for (int i = 0; i < 18; ++i) {
        const int I = wave * 18 + i;
        load_lds16(Wp + (size_t)I * 512 + lane * 8, (char*)wsb + (size_t)I * 1024);
    }

    const float* xp[2];
#pragma unroll
    for (int g = 0; g < 2; ++g)
        xp[g] = x + (rowg + wave * 32 + g * 16 + l16) * CDIM + quad * 8;

    floatx4 acc[2][12];
#pragma unroll
    for (int g = 0; g < 2; ++g)
#pragma unroll
        for (int i = 0; i < 12; ++i)
#pragma unroll
            for (int r = 0; r < 4; ++r) acc[g][i][r] = 0.f;

    floatx4 s0[2][2], s1[2][2], s2[2][2], s3[2][2], s4[2][2], s5[2][2];

#define XLOAD(cc, S) do { _Pragma("unroll")                                   \
    for (int g_ = 0; g_ < 2; ++g_) {                                          \
        S[g_][0] = *(const floatx4*)(xp[g_] + (cc) * 32);                     \
        S[g_][1] = *(const floatx4*)(xp[g_] + (cc) * 32 + 4);                 \
    }                                                                         \
} while (0)

#define CH(cc, CUR, NXT, lc) do {                                             \
    if ((lc) < 12) XLOAD(lc, NXT);                                            \
    half8 aF[2];                                                              \
    _Pragma("unroll")                                                         \
    for (int g_ = 0; g_ < 2; ++g_) {                                          \
        _Pragma("unroll")                                                     \
        for (int jj = 0; jj < 8; ++jj)                                        \
            aF[g_][jj] = (_Float16)(jj < 4 ? CUR[g_][0][jj]                   \
                                           : CUR[g_][1][jj - 4]);             \
    }                                                                         \
    const _Float16* bp = &wsb[cc][0] + ((size_t)quad * 192 + l16) * 8;        \
    _Pragma("unroll")                                                         \
    for (int i_ = 0; i_ < 12; ++i_) {                                         \
        half8 bb = *(const half8*)(bp + i_ * 128);                            \
        acc[0][i_] = __builtin_amdgcn_mfma_f32_16x16x32_f16(aF[0], bb, acc[0][i_], 0, 0, 0); \
        acc[1][i_] = __builtin_amdgcn_mfma_f32_16x16x32_f16(aF[1], bb, acc[1][i_], 0, 0, 0); \
    }                                                                         \
} while (0)

    // ---- fill the 5-deep x pipeline (20 loads), then wait W only ----
    XLOAD(0, s0); XLOAD(1, s1); XLOAD(2, s2); XLOAD(3, s3); XLOAD(4, s4);
    // queue (oldest first): 18 W DMAs, then 20 x loads. vmcnt(20) completes
    // exactly the W DMAs; all 20 x loads remain in flight.
    asm volatile("s_waitcnt vmcnt(20)" ::: "memory");
    __builtin_amdgcn_s_barrier();                        // W visible to all

    CH(0,  s0, s5, 5);   CH(1,  s1, s0, 6);   CH(2,  s2, s1, 7);
    CH(3,  s3, s2, 8);   CH(4,  s4, s3, 9);   CH(5,  s5, s4, 10);
    CH(6,  s0, s5, 11);  CH(7,  s1, s0, 12);  CH(8,  s2, s1, 13);
    CH(9,  s3, s2, 14);  CH(10, s4, s3, 15);  CH(11, s5, s4, 16);

#undef CH
#undef XLOAD

    // ---- epilogue: bias + RoPE; Q/K row-major, V transposed (b,d,t) ----
    float bq4[4], bk4[4], bv4[4];
#pragma unroll
    for (int s4_ = 0; s4_ < 4; ++s4_) {
        const int cc = s4_ * 16 + l16;
        bq4[s4_] = bq[cc]; bk4[s4_] = bk[cc]; bv4[s4_] = bv[cc];
    }
    const int bidx = row0 >> 9;                          // chunk-local batch

#pragma unroll
    for (int g = 0; g < 2; ++g) {
        const int t00  = (row0 & (TSEQ - 1)) + wave * 32 + g * 16 + quad * 4;
        const int rowb = row0 + wave * 32 + g * 16 + quad * 4;
#pragma unroll
        for (int r = 0; r < 4; ++r) {
            const int t = t00 + r;
            const float st = sinf((float)t);
            const float ct = cosf((float)t);
            const int row = rowb + r;
#pragma unroll
            for (int s4_ = 0; s4_ < 4; ++s4_) {
                const int cc = s4_ * 16 + l16;
                float vq = acc[g][s4_][r] + bq4[s4_];
                float pq = __shfl_xor(vq, 1);
                vq = (cc & 1) ? (pq * st + vq * ct) : (vq * ct - pq * st);
                Qw[(size_t)row * HD + cc] = (_Float16)(vq * QSCALE);
                float vk = acc[g][4 + s4_][r] + bk4[s4_];
                float pk = __shfl_xor(vk, 1);
                vk = (cc & 1) ? (pk * st + vk * ct) : (vk * ct - pk * st);
                Kw[(size_t)row * HD + cc] = (_Float16)vk;
            }
        }
        // V: pack 4 consecutive t per store (t = t00..t00+3 contiguous)
#pragma unroll
        for (int s4_ = 0; s4_ < 4; ++s4_) {
            const int cc = s4_ * 16 + l16;
            half4 vpack;
#pragma unroll
            for (int r = 0; r < 4; ++r)
                vpack[r] = (_Float16)(acc[g][8 + s4_][r] + bv4[s4_]);
            *(half4*)(Vtw + ((size_t)bidx * HD + cc) * TSEQ + t00) = vpack;
        }
    }
}

// ---------------------------------------------------------------------------
// Kernel D: causal flash attention (UNCHANGED from round 4 -- single-variable
// attribution). Grid (16, nb); each block owns ONE balanced strip pair
// (pr, 31-pr) = 9 tile-units; its 4 waves split the k-range by j mod 4 and
// merge through LDS at the end (exact: fixed-bias softmax -> partials
// additive). V loaded after K dies (-32 live VGPR). XCD swizzle keeps a
// batch's 16 blocks on one XCD.
// ---------------------------------------------------------------------------
__global__ __launch_bounds__(256, 3) void attn_kernel(
    const _Float16* __restrict__ Qw, const _Float16* __restrict__ Kw,
    const _Float16* __restrict__ Vtw, float* __restrict__ out, int b0)
{
    int bx, bl;
    {
        const int lin = blockIdx.y * 16 + blockIdx.x;
        if ((gridDim.y & 7) == 0) {                  // bijective XCD grouping
            const int per = gridDim.y >> 3;          // batches per XCD
            const int xcd = lin & 7;
            const int k2  = lin >> 3;                // [0, 2*nb)
            bl = xcd * per + (k2 >> 4);
            bx = k2 & 15;
        } else { bx = blockIdx.x; bl = blockIdx.y; }
    }
    const int tid  = threadIdx.x;
    const int wave = tid >> 6;
    const int lane = tid & 63;
    const int l16  = lane & 15;
    const int quad = lane >> 4;

    const int pr  = bx;                              // strip pair 0..15
    const int h   = wave;                            // k-phase (j mod 4)
    const int qA  = pr * 16;                         // near strip rows
    const int qB  = (31 - pr) * 16;                  // far strip rows
    const int jdA = pr >> 2;                         // diag tile, strip A
    const int jdB = (31 - pr) >> 2;                  // diag tile, strip B

    __shared__ __align__(16) _Float16 pbuf[4][16][72];
    __shared__ __align__(16) floatx4  mbuf[3][10][64];   // merge buffer

    const _Float16* Qb = Qw  + (size_t)bl * TSEQ * HD;
    const _Float16* Kb = Kw  + (size_t)bl * TSEQ * HD;
    const _Float16* Vb = Vtw + (size_t)bl * HD * TSEQ;   // [d][t]

    half8 aQA0 = *(const half8*)(Qb + (size_t)(qA + l16) * HD + quad * 8);
    half8 aQA1 = *(const half8*)(Qb + (size_t)(qA + l16) * HD + 32 + quad * 8);
    half8 aQB0 = *(const half8*)(Qb + (size_t)(qB + l16) * HD + quad * 8);
    half8 aQB1 = *(const half8*)(Qb + (size_t)(qB + l16) * HD + 32 + quad * 8);

    half8 ones;
#pragma unroll
    for (int jj = 0; jj < 8; ++jj) ones[jj] = (_Float16)1.f;

    floatx4 accO[8], accL[2];
#pragma unroll
    for (int i = 0; i < 8; ++i)
#pragma unroll
        for (int r = 0; r < 4; ++r) accO[i][r] = 0.f;
#pragma unroll
    for (int s = 0; s < 2; ++s)
#pragma unroll
        for (int r = 0; r < 4; ++r) accL[s][r] = 0.f;

    for (int j = h; j <= jdB; j += 4) {
        const int kb = j * 64;
        const bool actA = (j <= jdA);

        // ---- K fragments (shared by both strips; dead before V loads) ----
        half8 bK0[4], bK1[4];
#pragma unroll
        for (int s4 = 0; s4 < 4; ++s4) {
            const _Float16* kp = Kb + (size_t)(kb + s4 * 16 + l16) * HD + quad * 8;
            bK0[s4] = *(const half8*)(kp);
            bK1[s4] = *(const half8*)(kp + 32);
        }

        // ---- strip A: QK^T + exp -> pbuf (st4A dies before B's QK) ----
        if (actA) {
            floatx4 st4[4];
            __builtin_amdgcn_s_setprio(1);
#pragma unroll
            for (int s4 = 0; s4 < 4; ++s4) {
#pragma unroll
                for (int r = 0; r < 4; ++r) st4[s4][r] = 0.f;
                st4[s4] = __builtin_amdgcn_mfma_f32_16x16x32_f16(bK0[s4], aQA0, st4[s4], 0, 0, 0);
                st4[s4] = __builtin_amdgcn_mfma_f32_16x16x32_f16(bK1[s4], aQA1, st4[s4], 0, 0, 0);
            }
            __builtin_amdgcn_s_setprio(0);
            const int qrow = qA + l16;
#pragma unroll
            for (int s4 = 0; s4 < 4; ++s4) {
                half4 w;
#pragma unroll
                for (int r = 0; r < 4; ++r) {
                    float p = __expf(fminf(st4[s4][r], 18.f) - MBIAS);
                    if (j == jdA) {
                        const int kcol = kb + s4 * 16 + quad * 4 + r;
                        if (kcol > qrow) p = 0.f;
                    }
                    w[r] = (_Float16)p;
                }
                *(half4*)(&pbuf[wave][l16][s4 * 16 + quad * 4]) = w;
            }
        }

        // ---- strip B: QK^T (K dies here) ----
        floatx4 stB[4];
        __builtin_amdgcn_s_setprio(1);
#pragma unroll
        for (int s4 = 0; s4 < 4; ++s4) {
#pragma unroll
            for (int r = 0; r < 4; ++r) stB[s4][r] = 0.f;
            stB[s4] = __builtin_amdgcn_mfma_f32_16x16x32_f16(bK0[s4], aQB0, stB[s4], 0, 0, 0);
            stB[s4] = __builtin_amdgcn_mfma_f32_16x16x32_f16(bK1[s4], aQB1, stB[s4], 0, 0, 0);
        }
        __builtin_amdgcn_s_setprio(0);

        // ---- V fragments (allocator reuses K's registers) ----
        half8 bV0[4], bV1[4];
#pragma unroll
        for (int s4 = 0; s4 < 4; ++s4) {
            const _Float16* vp = Vb + (size_t)(s4 * 16 + l16) * TSEQ + kb + quad * 8;
            bV0[s4] = *(const half8*)(vp);
            bV1[s4] = *(const half8*)(vp + 32);
        }

        // ---- strip A: PV (pbuf read precedes B's pbuf overwrite) ----
        if (actA) {
            half8 aP0 = *(const half8*)(&pbuf[wave][l16][quad * 8]);
            half8 aP1 = *(const half8*)(&pbuf[wave][l16][32 + quad * 8]);
            __builtin_amdgcn_s_setprio(1);
#pragma unroll
            for (int s4 = 0; s4 < 4; ++s4) {
                accO[s4] = __builtin_amdgcn_mfma_f32_16x16x32_f16(aP0, bV0[s4], accO[s4], 0, 0, 0);
                accO[s4] = __builtin_amdgcn_mfma_f32_16x16x32_f16(aP1, bV1[s4], accO[s4], 0, 0, 0);
            }
            accL[0] = __builtin_amdgcn_mfma_f32_16x16x32_f16(aP0, ones, accL[0], 0, 0, 0);
            accL[0] = __builtin_amdgcn_mfma_f32_16x16x32_f16(aP1, ones, accL[0], 0, 0, 0);
            __builtin_amdgcn_s_setprio(0);
        }

        // ---- strip B: exp -> pbuf, PV ----
        {
            const int qrow = qB + l16;
#pragma unroll
            for (int s4 = 0; s4 < 4; ++s4) {
                half4 w;
#pragma unroll
                for (int r = 0; r < 4; ++r) {
                    float p = __expf(fminf(stB[s4][r], 18.f) - MBIAS);
                    if (j == jdB) {
                        const int kcol = kb + s4 * 16 + quad * 4 + r;
                        if (kcol > qrow) p = 0.f;
                    }
                    w[r] = (_Float16)p;
                }
                *(half4*)(&pbuf[wave][l16][s4 * 16 + quad * 4]) = w;
            }
            half8 aP0 = *(const half8*)(&pbuf[wave][l16][quad * 8]);
            half8 aP1 = *(const half8*)(&pbuf[wave][l16][32 + quad * 8]);
            __builtin_amdgcn_s_setprio(1);
#pragma unroll
            for (int s4 = 0; s4 < 4; ++s4) {
                accO[4 + s4] = __builtin_amdgcn_mfma_f32_16x16x32_f16(aP0, bV0[s4], accO[4 + s4], 0, 0, 0);
                accO[4 + s4] = __builtin_amdgcn_mfma_f32_16x16x32_f16(aP1, bV1[s4], accO[4 + s4], 0, 0, 0);
            }
            accL[1] = __builtin_amdgcn_mfma_f32_16x16x32_f16(aP0, ones, accL[1], 0, 0, 0);
            accL[1] = __builtin_amdgcn_mfma_f32_16x16x32_f16(aP1, ones, accL[1], 0, 0, 0);
            __builtin_amdgcn_s_setprio(0);
        }
    }

    // ---- merge the 4 k-phases (exact: fixed-bias softmax) ----
    if (h != 0) {
#pragma unroll
        for (int i = 0; i < 8; ++i) mbuf[h - 1][i][lane] = accO[i];
        mbuf[h - 1][8][lane] = accL[0];
        mbuf[h - 1][9][lane] = accL[1];
    }
    __syncthreads();
    if (h != 0) return;

#pragma unroll
    for (int m = 0; m < 3; ++m) {
#pragma unroll
        for (int i = 0; i < 8; ++i) {
            floatx4 t = mbuf[m][i][lane];
#pragma unroll
            for (int r = 0; r < 4; ++r) accO[i][r] += t[r];
        }
        floatx4 t8 = mbuf[m][8][lane];
        floatx4 t9 = mbuf[m][9][lane];
#pragma unroll
        for (int r = 0; r < 4; ++r) { accL[0][r] += t8[r]; accL[1][r] += t9[r]; }
    }

    // ---- epilogue (phase-0 wave writes both strips) ----
#pragma unroll
    for (int s = 0; s < 2; ++s) {
        const int qbase = (s == 0) ? qA : qB;
        float inv[4];
#pragma unroll
        for (int r = 0; r < 4; ++r) inv[r] = 1.f / accL[s][r];
#pragma unroll
        for (int s4 = 0; s4 < 4; ++s4) {
            const int dcol = s4 * 16 + l16;
#pragma unroll
            for (int r = 0; r < 4; ++r) {
                const int qr = qbase + quad * 4 + r;
                out[((size_t)(b0 + bl) * TSEQ + qr) * HD + dcol] =
                    accO[s * 4 + s4][r] * inv[r];
            }
        }
    }
}

// ---------------------------------------------------------------------------
extern "C" void kernel_launch(void* const* d_in, const int* in_sizes, int n_in,
                              void* d_out, int out_size, void* d_ws, size_t ws_size,
                              hipStream_t stream)
{
    char* ws = (char*)d_ws;
    _Float16* Wp = (_Float16*)ws;                           // 147456 B
    char* qkv_base = ws + 147456;

    const size_t per_b = (size_t)3 * TSEQ * HD * sizeof(_Float16);  // 196608 B
    size_t avail = (ws_size > (size_t)147456) ? ws_size - 147456 : per_b;
    int nbc = (int)(avail / per_b);
    if (nbc > NB) nbc = NB;
    if (nbc < 1)  nbc = 1;

    const size_t chunk_elems = (size_t)nbc * TSEQ * HD;
    _Float16* Qw  = (_Float16*)qkv_base;
    _Float16* Kw  = Qw + chunk_elems;
    _Float16* Vtw = Kw + chunk_elems;

    prep_w<<<dim3((3 * CDIM * HD + 255) / 256), dim3(256), 0, stream>>>(
        (const float*)d_in[1], (const float*)d_in[3], (const float*)d_in[5], Wp);

    for (int b0 = 0; b0 < NB; b0 += nbc) {
        const int nb = (NB - b0 < nbc) ? (NB - b0) : nbc;
        qkv_gemm<<<dim3(nb * 2), dim3(512), 0, stream>>>(
            (const float*)d_in[0], Wp, (const float*)d_in[2], (const float*)d_in[4],
            (const float*)d_in[6], Qw, Kw, Vtw, b0);
        attn_kernel<<<dim3(16, nb), dim3(256), 0, stream>>>(
            Qw, Kw, Vtw, (float*)d_out, b0);
    }
}

// Round 8
// 220.176 us; speedup vs baseline: 1.0216x; 1.0058x over previous
//
#include <hip/hip_runtime.h>

#define TSEQ 512
#define NB   128
#define CDIM 384
#define HD   64
#define QSCALE 0.051031036307982884f   // 384^-0.5, folded into Q at projection
#define MBIAS  8.0f                    // fixed softmax offset (exact: cancels in O=PV/l)

typedef _Float16 half8  __attribute__((ext_vector_type(8)));
typedef _Float16 half4  __attribute__((ext_vector_type(4)));
typedef float    floatx4 __attribute__((ext_vector_type(4)));

typedef __attribute__((address_space(3))) unsigned int lds_u32;
typedef const __attribute__((address_space(1))) unsigned int g_u32;

__device__ __forceinline__ void load_lds16(const void* g, void* l) {
    // async global->LDS DMA, 16B/lane; LDS dst = wave-uniform base + lane*16
    __builtin_amdgcn_global_load_lds((g_u32*)g, (lds_u32*)l, 16, 0, 0);
}

// ---------------------------------------------------------------------------
// Kernel B: pack the three 384x64 fp32 weights into the EXACT LDS staging
// order (12 chunks of BK=32):
//   Wp[c][kblk(4)][n(192)][kin(8)] = w_mat(n/64)[(c*32 + kblk*8 + kin)*64 + n%64]
// so qkv W staging is fully-contiguous 1-KB global_load_lds (linear copy).
// ---------------------------------------------------------------------------
__global__ void prep_w(const float* __restrict__ wq, const float* __restrict__ wk,
                       const float* __restrict__ wv, _Float16* __restrict__ Wp)
{
    int i = blockIdx.x * 256 + threadIdx.x;
    if (i >= 3 * CDIM * HD) return;                 // 73728
    int c    = i / 6144;  int r  = i - c * 6144;    // chunk (BK=32)
    int kblk = r / 1536;  int r2 = r - kblk * 1536;
    int n    = r2 >> 3;   int kin = r2 & 7;
    int k    = c * 32 + kblk * 8 + kin;
    int mat  = n / 64;    int col = n - mat * 64;
    const float* w = (mat == 0) ? wq : ((mat == 1) ? wk : wv);
    Wp[i] = (_Float16)w[k * HD + col];
}

// ---------------------------------------------------------------------------
// Kernel C: fused QKV projection -- NO-SPILL round.
// r7 post-mortem: __launch_bounds__(512) let the compiler cap VGPR at 128,
// but live state (acc[2][12]=96 + slot arrays) needs ~200 -> the x "register
// stream" was SPILLED TO SCRATCH. Proof: WRITE_SIZE 57 MB vs 25 MB of real
// output (r6, low-pressure, wrote exactly 24576 KB); ~48 MB/dispatch of
// spill R/W ran through HBM inside the K-loop.
// Fix (single change): __launch_bounds__(512, 2) -- 8 waves = exactly
// 2 waves/SIMD (1 block/CU, LDS-capped), so 256 VGPR/wave is legal; depth
// trimmed to 4 (5 rotating slots = 80 VGPR, total live ~206 < 256).
// Skeleton unchanged from r7: entire 144-KiB packed W resident in LDS,
// staged once via 18 DMAs/wave issued FIRST; then 16 x-loads (4 chunks);
// vmcnt(16) completes exactly the W DMAs, keeping all x loads in flight;
// K-loop has zero barriers / zero inter-wave coupling.
// Epilogue: bias + RoPE (fres==1 -> angle=t) via shfl_xor 1; Q scaled.
// Q,K (b,t,d) fp16; V transposed (b,d,t) fp16.
// ---------------------------------------------------------------------------
__global__ __launch_bounds__(512, 2) void qkv_gemm(
    const float* __restrict__ x, const _Float16* __restrict__ Wp,
    const float* __restrict__ bq, const float* __restrict__ bk,
    const float* __restrict__ bv,
    _Float16* __restrict__ Qw, _Float16* __restrict__ Kw,
    _Float16* __restrict__ Vtw, int b0)
{
    __shared__ __align__(16) _Float16 wsb[12][6144];     // 144 KiB, resident W

    const int tid  = threadIdx.x;
    const int wave = tid >> 6;                           // 0..7
    const int lane = tid & 63;
    const int l16  = lane & 15;
    const int quad = lane >> 4;

    const int row0 = blockIdx.x * 256;                   // chunk-local row base
    const size_t rowg = (size_t)b0 * TSEQ + row0;        // global row base

    // ---- stage ALL of W: 144 linear 1-KB DMAs, 18 per wave (issued FIRST) --
#pragma unroll
    for (int i = 0; i < 18; ++i) {
        const int I = wave * 18 + i;
        load_lds16(Wp + (size_t)I * 512 + lane * 8, (char*)wsb + (size_t)I * 1024);
    }

    const float* xp[2];
#pragma unroll
    for (int g = 0; g < 2; ++g)
        xp[g] = x + (rowg + wave * 32 + g * 16 + l16) * CDIM + quad * 8;

    floatx4 acc[2][12];
#pragma unroll
    for (int g = 0; g < 2; ++g)
#pragma unroll
        for (int i = 0; i < 12; ++i)
#pragma unroll
            for (int r = 0; r < 4; ++r) acc[g][i][r] = 0.f;

    floatx4 s0[2][2], s1[2][2], s2[2][2], s3[2][2], s4[2][2];  // 5 slots, depth 4

#define XLOAD(cc, S) do { _Pragma("unroll")                                   \
    for (int g_ = 0; g_ < 2; ++g_) {                                          \
        S[g_][0] = *(const floatx4*)(xp[g_] + (cc) * 32);                     \
        S[g_][1] = *(const floatx4*)(xp[g_] + (cc) * 32 + 4);                 \
    }                                                                         \
} while (0)

#define CH(cc, CUR, NXT, lc) do {                                             \
    if ((lc) < 12) XLOAD(lc, NXT);                                            \
    half8 aF[2];                                                              \
    _Pragma("unroll")                                                         \
    for (int g_ = 0; g_ < 2; ++g_) {                                          \
        _Pragma("unroll")                                                     \
        for (int jj = 0; jj < 8; ++jj)                                        \
            aF[g_][jj] = (_Float16)(jj < 4 ? CUR[g_][0][jj]                   \
                                           : CUR[g_][1][jj - 4]);             \
    }                                                                         \
    const _Float16* bp = &wsb[cc][0] + ((size_t)quad * 192 + l16) * 8;        \
    _Pragma("unroll")                                                         \
    for (int i_ = 0; i_ < 12; ++i_) {                                         \
        half8 bb = *(const half8*)(bp + i_ * 128);                            \
        acc[0][i_] = __builtin_amdgcn_mfma_f32_16x16x32_f16(aF[0], bb, acc[0][i_], 0, 0, 0); \
        acc[1][i_] = __builtin_amdgcn_mfma_f32_16x16x32_f16(aF[1], bb, acc[1][i_], 0, 0, 0); \
    }                                                                         \
} while (0)

    // ---- fill the 4-deep x pipeline (16 loads), then wait W only ----
    XLOAD(0, s0); XLOAD(1, s1); XLOAD(2, s2); XLOAD(3, s3);
    // queue (oldest first): 18 W DMAs, then 16 x loads. vmcnt(16) completes
    // exactly the W DMAs; all 16 x loads remain in flight.
    asm volatile("s_waitcnt vmcnt(16)" ::: "memory");
    __builtin_amdgcn_s_barrier();                        // W visible to all

    // slot for chunk c = c % 5; load target for chunk lc = lc % 5
    CH(0,  s0, s4, 4);   CH(1,  s1, s0, 5);   CH(2,  s2, s1, 6);
    CH(3,  s3, s2, 7);   CH(4,  s4, s3, 8);   CH(5,  s0, s4, 9);
    CH(6,  s1, s0, 10);  CH(7,  s2, s1, 11);  CH(8,  s3, s2, 12);
    CH(9,  s4, s3, 12);  CH(10, s0, s4, 12);  CH(11, s1, s0, 12);

#undef CH
#undef XLOAD

    // ---- epilogue: bias + RoPE; Q/K row-major, V transposed (b,d,t) ----
    float bq4[4], bk4[4], bv4[4];
#pragma unroll
    for (int s4_ = 0; s4_ < 4; ++s4_) {
        const int cc = s4_ * 16 + l16;
        bq4[s4_] = bq[cc]; bk4[s4_] = bk[cc]; bv4[s4_] = bv[cc];
    }
    const int bidx = row0 >> 9;                          // chunk-local batch

#pragma unroll
    for (int g = 0; g < 2; ++g) {
        const int t00  = (row0 & (TSEQ - 1)) + wave * 32 + g * 16 + quad * 4;
        const int rowb = row0 + wave * 32 + g * 16 + quad * 4;
#pragma unroll
        for (int r = 0; r < 4; ++r) {
            const int t = t00 + r;
            const float st = sinf((float)t);
            const float ct = cosf((float)t);
            const int row = rowb + r;
#pragma unroll
            for (int s4_ = 0; s4_ < 4; ++s4_) {
                const int cc = s4_ * 16 + l16;
                float vq = acc[g][s4_][r] + bq4[s4_];
                float pq = __shfl_xor(vq, 1);
                vq = (cc & 1) ? (pq * st + vq * ct) : (vq * ct - pq * st);
                Qw[(size_t)row * HD + cc] = (_Float16)(vq * QSCALE);
                float vk = acc[g][4 + s4_][r] + bk4[s4_];
                float pk = __shfl_xor(vk, 1);
                vk = (cc & 1) ? (pk * st + vk * ct) : (vk * ct - pk * st);
                Kw[(size_t)row * HD + cc] = (_Float16)vk;
            }
        }
        // V: pack 4 consecutive t per store (t = t00..t00+3 contiguous)
#pragma unroll
        for (int s4_ = 0; s4_ < 4; ++s4_) {
            const int cc = s4_ * 16 + l16;
            half4 vpack;
#pragma unroll
            for (int r = 0; r < 4; ++r)
                vpack[r] = (_Float16)(acc[g][8 + s4_][r] + bv4[s4_]);
            *(half4*)(Vtw + ((size_t)bidx * HD + cc) * TSEQ + t00) = vpack;
        }
    }
}

// ---------------------------------------------------------------------------
// Kernel D: causal flash attention (UNCHANGED from round 4 -- single-variable
// attribution). Grid (16, nb); each block owns ONE balanced strip pair
// (pr, 31-pr) = 9 tile-units; its 4 waves split the k-range by j mod 4 and
// merge through LDS at the end (exact: fixed-bias softmax -> partials
// additive). V loaded after K dies (-32 live VGPR). XCD swizzle keeps a
// batch's 16 blocks on one XCD.
// ---------------------------------------------------------------------------
__global__ __launch_bounds__(256, 3) void attn_kernel(
    const _Float16* __restrict__ Qw, const _Float16* __restrict__ Kw,
    const _Float16* __restrict__ Vtw, float* __restrict__ out, int b0)
{
    int bx, bl;
    {
        const int lin = blockIdx.y * 16 + blockIdx.x;
        if ((gridDim.y & 7) == 0) {                  // bijective XCD grouping
            const int per = gridDim.y >> 3;          // batches per XCD
            const int xcd = lin & 7;
            const int k2  = lin >> 3;                // [0, 2*nb)
            bl = xcd * per + (k2 >> 4);
            bx = k2 & 15;
        } else { bx = blockIdx.x; bl = blockIdx.y; }
    }
    const int tid  = threadIdx.x;
    const int wave = tid >> 6;
    const int lane = tid & 63;
    const int l16  = lane & 15;
    const int quad = lane >> 4;

    const int pr  = bx;                              // strip pair 0..15
    const int h   = wave;                            // k-phase (j mod 4)
    const int qA  = pr * 16;                         // near strip rows
    const int qB  = (31 - pr) * 16;                  // far strip rows
    const int jdA = pr >> 2;                         // diag tile, strip A
    const int jdB = (31 - pr) >> 2;                  // diag tile, strip B

    __shared__ __align__(16) _Float16 pbuf[4][16][72];
    __shared__ __align__(16) floatx4  mbuf[3][10][64];   // merge buffer

    const _Float16* Qb = Qw  + (size_t)bl * TSEQ * HD;
    const _Float16* Kb = Kw  + (size_t)bl * TSEQ * HD;
    const _Float16* Vb = Vtw + (size_t)bl * HD * TSEQ;   // [d][t]

    half8 aQA0 = *(const half8*)(Qb + (size_t)(qA + l16) * HD + quad * 8);
    half8 aQA1 = *(const half8*)(Qb + (size_t)(qA + l16) * HD + 32 + quad * 8);
    half8 aQB0 = *(const half8*)(Qb + (size_t)(qB + l16) * HD + quad * 8);
    half8 aQB1 = *(const half8*)(Qb + (size_t)(qB + l16) * HD + 32 + quad * 8);

    half8 ones;
#pragma unroll
    for (int jj = 0; jj < 8; ++jj) ones[jj] = (_Float16)1.f;

    floatx4 accO[8], accL[2];
#pragma unroll
    for (int i = 0; i < 8; ++i)
#pragma unroll
        for (int r = 0; r < 4; ++r) accO[i][r] = 0.f;
#pragma unroll
    for (int s = 0; s < 2; ++s)
#pragma unroll
        for (int r = 0; r < 4; ++r) accL[s][r] = 0.f;

    for (int j = h; j <= jdB; j += 4) {
        const int kb = j * 64;
        const bool actA = (j <= jdA);

        // ---- K fragments (shared by both strips; dead before V loads) ----
        half8 bK0[4], bK1[4];
#pragma unroll
        for (int s4 = 0; s4 < 4; ++s4) {
            const _Float16* kp = Kb + (size_t)(kb + s4 * 16 + l16) * HD + quad * 8;
            bK0[s4] = *(const half8*)(kp);
            bK1[s4] = *(const half8*)(kp + 32);
        }

        // ---- strip A: QK^T + exp -> pbuf (st4A dies before B's QK) ----
        if (actA) {
            floatx4 st4[4];
            __builtin_amdgcn_s_setprio(1);
#pragma unroll
            for (int s4 = 0; s4 < 4; ++s4) {
#pragma unroll
                for (int r = 0; r < 4; ++r) st4[s4][r] = 0.f;
                st4[s4] = __builtin_amdgcn_mfma_f32_16x16x32_f16(bK0[s4], aQA0, st4[s4], 0, 0, 0);
                st4[s4] = __builtin_amdgcn_mfma_f32_16x16x32_f16(bK1[s4], aQA1, st4[s4], 0, 0, 0);
            }
            __builtin_amdgcn_s_setprio(0);
            const int qrow = qA + l16;
#pragma unroll
            for (int s4 = 0; s4 < 4; ++s4) {
                half4 w;
#pragma unroll
                for (int r = 0; r < 4; ++r) {
                    float p = __expf(fminf(st4[s4][r], 18.f) - MBIAS);
                    if (j == jdA) {
                        const int kcol = kb + s4 * 16 + quad * 4 + r;
                        if (kcol > qrow) p = 0.f;
                    }
                    w[r] = (_Float16)p;
                }
                *(half4*)(&pbuf[wave][l16][s4 * 16 + quad * 4]) = w;
            }
        }

        // ---- strip B: QK^T (K dies here) ----
        floatx4 stB[4];
        __builtin_amdgcn_s_setprio(1);
#pragma unroll
        for (int s4 = 0; s4 < 4; ++s4) {
#pragma unroll
            for (int r = 0; r < 4; ++r) stB[s4][r] = 0.f;
            stB[s4] = __builtin_amdgcn_mfma_f32_16x16x32_f16(bK0[s4], aQB0, stB[s4], 0, 0, 0);
            stB[s4] = __builtin_amdgcn_mfma_f32_16x16x32_f16(bK1[s4], aQB1, stB[s4], 0, 0, 0);
        }
        __builtin_amdgcn_s_setprio(0);

        // ---- V fragments (allocator reuses K's registers) ----
        half8 bV0[4], bV1[4];
#pragma unroll
        for (int s4 = 0; s4 < 4; ++s4) {
            const _Float16* vp = Vb + (size_t)(s4 * 16 + l16) * TSEQ + kb + quad * 8;
            bV0[s4] = *(const half8*)(vp);
            bV1[s4] = *(const half8*)(vp + 32);
        }

        // ---- strip A: PV (pbuf read precedes B's pbuf overwrite) ----
        if (actA) {
            half8 aP0 = *(const half8*)(&pbuf[wave][l16][quad * 8]);
            half8 aP1 = *(const half8*)(&pbuf[wave][l16][32 + quad * 8]);
            __builtin_amdgcn_s_setprio(1);
#pragma unroll
            for (int s4 = 0; s4 < 4; ++s4) {
                accO[s4] = __builtin_amdgcn_mfma_f32_16x16x32_f16(aP0, bV0[s4], accO[s4], 0, 0, 0);
                accO[s4] = __builtin_amdgcn_mfma_f32_16x16x32_f16(aP1, bV1[s4], accO[s4], 0, 0, 0);
            }
            accL[0] = __builtin_amdgcn_mfma_f32_16x16x32_f16(aP0, ones, accL[0], 0, 0, 0);
            accL[0] = __builtin_amdgcn_mfma_f32_16x16x32_f16(aP1, ones, accL[0], 0, 0, 0);
            __builtin_amdgcn_s_setprio(0);
        }

        // ---- strip B: exp -> pbuf, PV ----
        {
            const int qrow = qB + l16;
#pragma unroll
            for (int s4 = 0; s4 < 4; ++s4) {
                half4 w;
#pragma unroll
                for (int r = 0; r < 4; ++r) {
                    float p = __expf(fminf(stB[s4][r], 18.f) - MBIAS);
                    if (j == jdB) {
                        const int kcol = kb + s4 * 16 + quad * 4 + r;
                        if (kcol > qrow) p = 0.f;
                    }
                    w[r] = (_Float16)p;
                }
                *(half4*)(&pbuf[wave][l16][s4 * 16 + quad * 4]) = w;
            }
            half8 aP0 = *(const half8*)(&pbuf[wave][l16][quad * 8]);
            half8 aP1 = *(const half8*)(&pbuf[wave][l16][32 + quad * 8]);
            __builtin_amdgcn_s_setprio(1);
#pragma unroll
            for (int s4 = 0; s4 < 4; ++s4) {
                accO[4 + s4] = __builtin_amdgcn_mfma_f32_16x16x32_f16(aP0, bV0[s4], accO[4 + s4], 0, 0, 0);
                accO[4 + s4] = __builtin_amdgcn_mfma_f32_16x16x32_f16(aP1, bV1[s4], accO[4 + s4], 0, 0, 0);
            }
            accL[1] = __builtin_amdgcn_mfma_f32_16x16x32_f16(aP0, ones, accL[1], 0, 0, 0);
            accL[1] = __builtin_amdgcn_mfma_f32_16x16x32_f16(aP1, ones, accL[1], 0, 0, 0);
            __builtin_amdgcn_s_setprio(0);
        }
    }

    // ---- merge the 4 k-phases (exact: fixed-bias softmax) ----
    if (h != 0) {
#pragma unroll
        for (int i = 0; i < 8; ++i) mbuf[h - 1][i][lane] = accO[i];
        mbuf[h - 1][8][lane] = accL[0];
        mbuf[h - 1][9][lane] = accL[1];
    }
    __syncthreads();
    if (h != 0) return;

#pragma unroll
    for (int m = 0; m < 3; ++m) {
#pragma unroll
        for (int i = 0; i < 8; ++i) {
            floatx4 t = mbuf[m][i][lane];
#pragma unroll
            for (int r = 0; r < 4; ++r) accO[i][r] += t[r];
        }
        floatx4 t8 = mbuf[m][8][lane];
        floatx4 t9 = mbuf[m][9][lane];
#pragma unroll
        for (int r = 0; r < 4; ++r) { accL[0][r] += t8[r]; accL[1][r] += t9[r]; }
    }

    // ---- epilogue (phase-0 wave writes both strips) ----
#pragma unroll
    for (int s = 0; s < 2; ++s) {
        const int qbase = (s == 0) ? qA : qB;
        float inv[4];
#pragma unroll
        for (int r = 0; r < 4; ++r) inv[r] = 1.f / accL[s][r];
#pragma unroll
        for (int s4 = 0; s4 < 4; ++s4) {
            const int dcol = s4 * 16 + l16;
#pragma unroll
            for (int r = 0; r < 4; ++r) {
                const int qr = qbase + quad * 4 + r;
                out[((size_t)(b0 + bl) * TSEQ + qr) * HD + dcol] =
                    accO[s * 4 + s4][r] * inv[r];
            }
        }
    }
}

// ---------------------------------------------------------------------------
extern "C" void kernel_launch(void* const* d_in, const int* in_sizes, int n_in,
                              void* d_out, int out_size, void* d_ws, size_t ws_size,
                              hipStream_t stream)
{
    char* ws = (char*)d_ws;
    _Float16* Wp = (_Float16*)ws;                           // 147456 B
    char* qkv_base = ws + 147456;

    const size_t per_b = (size_t)3 * TSEQ * HD * sizeof(_Float16);  // 196608 B
    size_t avail = (ws_size > (size_t)147456) ? ws_size - 147456 : per_b;
    int nbc = (int)(avail / per_b);
    if (nbc > NB) nbc = NB;
    if (nbc < 1)  nbc = 1;

    const size_t chunk_elems = (size_t)nbc * TSEQ * HD;
    _Float16* Qw  = (_Float16*)qkv_base;
    _Float16* Kw  = Qw + chunk_elems;
    _Float16* Vtw = Kw + chunk_elems;

    prep_w<<<dim3((3 * CDIM * HD + 255) / 256), dim3(256), 0, stream>>>(
        (const float*)d_in[1], (const float*)d_in[3], (const float*)d_in[5], Wp);

    for (int b0 = 0; b0 < NB; b0 += nbc) {
        const int nb = (NB - b0 < nbc) ? (NB - b0) : nbc;
        qkv_gemm<<<dim3(nb * 2), dim3(512), 0, stream>>>(
            (const float*)d_in[0], Wp, (const float*)d_in[2], (const float*)d_in[4],
            (const float*)d_in[6], Qw, Kw, Vtw, b0);
        attn_kernel<<<dim3(16, nb), dim3(256), 0, stream>>>(
            Qw, Kw, Vtw, (float*)d_out, b0);
    }
}

// Round 11
// 205.151 us; speedup vs baseline: 1.0964x; 1.0732x over previous
//
#include <hip/hip_runtime.h>

#define TSEQ 512
#define NB   128
#define CDIM 384
#define HD   64
#define QSCALE 0.051031036307982884f   // 384^-0.5, folded into Q at projection
#define MBIAS  8.0f                    // fixed softmax offset (exact: cancels in O=PV/l)

typedef _Float16 half8  __attribute__((ext_vector_type(8)));
typedef _Float16 half4  __attribute__((ext_vector_type(4)));
typedef float    floatx4 __attribute__((ext_vector_type(4)));

typedef __attribute__((address_space(3))) unsigned int lds_u32;
typedef const __attribute__((address_space(1))) unsigned int g_u32;

__device__ __forceinline__ void load_lds16(const void* g, void* l) {
    // async global->LDS DMA, 16B/lane; LDS dst = wave-uniform base + lane*16
    __builtin_amdgcn_global_load_lds((g_u32*)g, (lds_u32*)l, 16, 0, 0);
}

// ---------------------------------------------------------------------------
// Kernel B: pack the three 384x64 fp32 weights into the EXACT LDS staging
// order (12 chunks of BK=32):
//   Wp[c][kblk(4)][n(192)][kin(8)] = w_mat(n/64)[(c*32 + kblk*8 + kin)*64 + n%64]
// so qkv W staging is fully-contiguous 1-KB global_load_lds (linear copy).
// ---------------------------------------------------------------------------
__global__ void prep_w(const float* __restrict__ wq, const float* __restrict__ wk,
                       const float* __restrict__ wv, _Float16* __restrict__ Wp)
{
    int i = blockIdx.x * 256 + threadIdx.x;
    if (i >= 3 * CDIM * HD) return;                 // 73728
    int c    = i / 6144;  int r  = i - c * 6144;    // chunk (BK=32)
    int kblk = r / 1536;  int r2 = r - kblk * 1536;
    int n    = r2 >> 3;   int kin = r2 & 7;
    int k    = c * 32 + kblk * 8 + kin;
    int mat  = n / 64;    int col = n - mat * 64;
    const float* w = (mat == 0) ? wq : ((mat == 1) ? wk : wv);
    Wp[i] = (_Float16)w[k * HD + col];
}

// ---------------------------------------------------------------------------
// Kernel C: fused QKV projection -- FIT-IN-128 round (THIRD submission: r9
// and r10 both died in container acquisition with no timing data; full
// hazard audit x2 found no OOB / no hang path / no resource overrun, and
// every construct here ran in r5/r7/r8. If this fails a third time the
// kernel-infra correlation becomes real and the next round restructures.)
// r8 post-mortem: spill theory CONFIRMED (r6, no-spill, wrote exactly
// 24576 KB; r5/r7/r8 wrote ~59 MB) but launch_bounds(512,2) did NOT raise
// the cap -- all three 512-thread variants pinned at exactly 128 VGPR.
// Empirical toolchain rule: 512-thread blocks get 128 VGPRs. So this round
// fits in 128 BY CONSTRUCTION instead of fighting the allocator:
//   wave owns 16 rows -> acc[12] = 48 VGPR (was 96);
//   x slots = 2 float4/lane = 8 VGPR each; 5 rotating slots, depth 4 = 40;
//   total live ~110 < 128 -> no spills possible.
// Cost: B-fragment ds_reads double (12 per wave per chunk for 16 rows) --
// LDS has ~10x headroom and zero conflicts (r5-r8 counters).
// Skeleton unchanged: entire 144-KiB packed W resident in LDS, staged once
// (18 DMAs/wave, issued FIRST); prologue vmcnt(8) completes exactly the W
// DMAs while all 8 x prefetch loads stay in flight; K-loop has zero
// barriers / zero inter-wave coupling; compiler inserts minimal waitcnt
// for each slot's register dependency.
// Geometry: 512 threads = 8 waves x 16 rows = 128 rows/block, grid nb*4;
// 1 block/CU (LDS-capped), 2 waves/SIMD.
// Epilogue: bias + RoPE (fres==1 -> angle=t) via shfl_xor 1; Q scaled.
// Q,K (b,t,d) fp16; V transposed (b,d,t) fp16.
// ---------------------------------------------------------------------------
__global__ __launch_bounds__(512) void qkv_gemm(
    const float* __restrict__ x, const _Float16* __restrict__ Wp,
    const float* __restrict__ bq, const float* __restrict__ bk,
    const float* __restrict__ bv,
    _Float16* __restrict__ Qw, _Float16* __restrict__ Kw,
    _Float16* __restrict__ Vtw, int b0)
{
    __shared__ __align__(16) _Float16 wsb[12][6144];     // 144 KiB, resident W

    const int tid  = threadIdx.x;
    const int wave = tid >> 6;                           // 0..7
    const int lane = tid & 63;
    const int l16  = lane & 15;
    const int quad = lane >> 4;

    const int row0 = blockIdx.x * 128;                   // chunk-local row base
    const size_t rowg = (size_t)b0 * TSEQ + row0;        // global row base

    // ---- stage ALL of W: 144 linear 1-KB DMAs, 18 per wave (issued FIRST) --
#pragma unroll
    for (int i = 0; i < 18; ++i) {
        const int I = wave * 18 + i;
        load_lds16(Wp + (size_t)I * 512 + lane * 8, (char*)wsb + (size_t)I * 1024);
    }

    const float* xp = x + (rowg + wave * 16 + l16) * CDIM + quad * 8;

    floatx4 acc[12];
#pragma unroll
    for (int i = 0; i < 12; ++i)
#pragma unroll
        for (int r = 0; r < 4; ++r) acc[i][r] = 0.f;

    floatx4 s0[2], s1[2], s2[2], s3[2], s4[2];           // 5 slots, depth 4

#define XLOAD(cc, S) do {                                                     \
    S[0] = *(const floatx4*)(xp + (cc) * 32);                                 \
    S[1] = *(const floatx4*)(xp + (cc) * 32 + 4);                             \
} while (0)

#define CH(cc, CUR, NXT, lc) do {                                             \
    if ((lc) < 12) XLOAD(lc, NXT);                                            \
    half8 aF;                                                                 \
    _Pragma("unroll")                                                         \
    for (int jj = 0; jj < 8; ++jj)                                            \
        aF[jj] = (_Float16)(jj < 4 ? CUR[0][jj] : CUR[1][jj - 4]);            \
    const _Float16* bp = &wsb[cc][0] + ((size_t)quad * 192 + l16) * 8;        \
    _Pragma("unroll")                                                         \
    for (int i_ = 0; i_ < 12; ++i_) {                                         \
        half8 bb = *(const half8*)(bp + i_ * 128);                            \
        acc[i_] = __builtin_amdgcn_mfma_f32_16x16x32_f16(aF, bb, acc[i_], 0, 0, 0); \
    }                                                                         \
} while (0)

    // ---- fill the 4-deep x pipeline (8 loads), then wait W only ----
    XLOAD(0, s0); XLOAD(1, s1); XLOAD(2, s2); XLOAD(3, s3);
    // queue (oldest first): 18 W DMAs, then 8 x loads. vmcnt(8) completes
    // exactly the W DMAs; all 8 x loads remain in flight.
    asm volatile("s_waitcnt vmcnt(8)" ::: "memory");
    __builtin_amdgcn_s_barrier();                        // W visible to all

    // slot(c) = c % 5; prefetch target lc = c + 4 lands in slot (c+4)%5,
    // which holds already-consumed chunk c-1 -- never the live CUR.
    CH(0,  s0, s4, 4);   CH(1,  s1, s0, 5);   CH(2,  s2, s1, 6);
    CH(3,  s3, s2, 7);   CH(4,  s4, s3, 8);   CH(5,  s0, s4, 9);
    CH(6,  s1, s0, 10);  CH(7,  s2, s1, 11);  CH(8,  s3, s2, 12);
    CH(9,  s4, s3, 12);  CH(10, s0, s4, 12);  CH(11, s1, s0, 12);

#undef CH
#undef XLOAD

    // ---- epilogue: bias + RoPE; Q/K row-major, V transposed (b,d,t) ----
    float bq4[4], bk4[4], bv4[4];
#pragma unroll
    for (int s4_ = 0; s4_ < 4; ++s4_) {
        const int cc = s4_ * 16 + l16;
        bq4[s4_] = bq[cc]; bk4[s4_] = bk[cc]; bv4[s4_] = bv[cc];
    }
    const int bidx = row0 >> 9;                          // chunk-local batch
    const int t00  = (row0 & (TSEQ - 1)) + wave * 16 + quad * 4;
    const int rowb = row0 + wave * 16 + quad * 4;

#pragma unroll
    for (int r = 0; r < 4; ++r) {
        const int t = t00 + r;
        const float st = sinf((float)t);
        const float ct = cosf((float)t);
        const int row = rowb + r;
#pragma unroll
        for (int s4_ = 0; s4_ < 4; ++s4_) {
            const int cc = s4_ * 16 + l16;
            float vq = acc[s4_][r] + bq4[s4_];
            float pq = __shfl_xor(vq, 1);
            vq = (cc & 1) ? (pq * st + vq * ct) : (vq * ct - pq * st);
            Qw[(size_t)row * HD + cc] = (_Float16)(vq * QSCALE);
            float vk = acc[4 + s4_][r] + bk4[s4_];
            float pk = __shfl_xor(vk, 1);
            vk = (cc & 1) ? (pk * st + vk * ct) : (vk * ct - pk * st);
            Kw[(size_t)row * HD + cc] = (_Float16)vk;
        }
    }
    // V: pack 4 consecutive t per store (t = t00..t00+3 contiguous)
#pragma unroll
    for (int s4_ = 0; s4_ < 4; ++s4_) {
        const int cc = s4_ * 16 + l16;
        half4 vpack;
#pragma unroll
        for (int r = 0; r < 4; ++r) vpack[r] = (_Float16)(acc[8 + s4_][r] + bv4[s4_]);
        *(half4*)(Vtw + ((size_t)bidx * HD + cc) * TSEQ + t00) = vpack;
    }
}

// ---------------------------------------------------------------------------
// Kernel D: causal flash attention (UNCHANGED from round 4 -- single-variable
// attribution). Grid (16, nb); each block owns ONE balanced strip pair
// (pr, 31-pr) = 9 tile-units; its 4 waves split the k-range by j mod 4 and
// merge through LDS at the end (exact: fixed-bias softmax -> partials
// additive). V loaded after K dies (-32 live VGPR). XCD swizzle keeps a
// batch's 16 blocks on one XCD.
// ---------------------------------------------------------------------------
__global__ __launch_bounds__(256, 3) void attn_kernel(
    const _Float16* __restrict__ Qw, const _Float16* __restrict__ Kw,
    const _Float16* __restrict__ Vtw, float* __restrict__ out, int b0)
{
    int bx, bl;
    {
        const int lin = blockIdx.y * 16 + blockIdx.x;
        if ((gridDim.y & 7) == 0) {                  // bijective XCD grouping
            const int per = gridDim.y >> 3;          // batches per XCD
            const int xcd = lin & 7;
            const int k2  = lin >> 3;                // [0, 2*nb)
            bl = xcd * per + (k2 >> 4);
            bx = k2 & 15;
        } else { bx = blockIdx.x; bl = blockIdx.y; }
    }
    const int tid  = threadIdx.x;
    const int wave = tid >> 6;
    const int lane = tid & 63;
    const int l16  = lane & 15;
    const int quad = lane >> 4;

    const int pr  = bx;                              // strip pair 0..15
    const int h   = wave;                            // k-phase (j mod 4)
    const int qA  = pr * 16;                         // near strip rows
    const int qB  = (31 - pr) * 16;                  // far strip rows
    const int jdA = pr >> 2;                         // diag tile, strip A
    const int jdB = (31 - pr) >> 2;                  // diag tile, strip B

    __shared__ __align__(16) _Float16 pbuf[4][16][72];
    __shared__ __align__(16) floatx4  mbuf[3][10][64];   // merge buffer

    const _Float16* Qb = Qw  + (size_t)bl * TSEQ * HD;
    const _Float16* Kb = Kw  + (size_t)bl * TSEQ * HD;
    const _Float16* Vb = Vtw + (size_t)bl * HD * TSEQ;   // [d][t]

    half8 aQA0 = *(const half8*)(Qb + (size_t)(qA + l16) * HD + quad * 8);
    half8 aQA1 = *(const half8*)(Qb + (size_t)(qA + l16) * HD + 32 + quad * 8);
    half8 aQB0 = *(const half8*)(Qb + (size_t)(qB + l16) * HD + quad * 8);
    half8 aQB1 = *(const half8*)(Qb + (size_t)(qB + l16) * HD + 32 + quad * 8);

    half8 ones;
#pragma unroll
    for (int jj = 0; jj < 8; ++jj) ones[jj] = (_Float16)1.f;

    floatx4 accO[8], accL[2];
#pragma unroll
    for (int i = 0; i < 8; ++i)
#pragma unroll
        for (int r = 0; r < 4; ++r) accO[i][r] = 0.f;
#pragma unroll
    for (int s = 0; s < 2; ++s)
#pragma unroll
        for (int r = 0; r < 4; ++r) accL[s][r] = 0.f;

    for (int j = h; j <= jdB; j += 4) {
        const int kb = j * 64;
        const bool actA = (j <= jdA);

        // ---- K fragments (shared by both strips; dead before V loads) ----
        half8 bK0[4], bK1[4];
#pragma unroll
        for (int s4 = 0; s4 < 4; ++s4) {
            const _Float16* kp = Kb + (size_t)(kb + s4 * 16 + l16) * HD + quad * 8;
            bK0[s4] = *(const half8*)(kp);
            bK1[s4] = *(const half8*)(kp + 32);
        }

        // ---- strip A: QK^T + exp -> pbuf (st4A dies before B's QK) ----
        if (actA) {
            floatx4 st4[4];
            __builtin_amdgcn_s_setprio(1);
#pragma unroll
            for (int s4 = 0; s4 < 4; ++s4) {
#pragma unroll
                for (int r = 0; r < 4; ++r) st4[s4][r] = 0.f;
                st4[s4] = __builtin_amdgcn_mfma_f32_16x16x32_f16(bK0[s4], aQA0, st4[s4], 0, 0, 0);
                st4[s4] = __builtin_amdgcn_mfma_f32_16x16x32_f16(bK1[s4], aQA1, st4[s4], 0, 0, 0);
            }
            __builtin_amdgcn_s_setprio(0);
            const int qrow = qA + l16;
#pragma unroll
            for (int s4 = 0; s4 < 4; ++s4) {
                half4 w;
#pragma unroll
                for (int r = 0; r < 4; ++r) {
                    float p = __expf(fminf(st4[s4][r], 18.f) - MBIAS);
                    if (j == jdA) {
                        const int kcol = kb + s4 * 16 + quad * 4 + r;
                        if (kcol > qrow) p = 0.f;
                    }
                    w[r] = (_Float16)p;
                }
                *(half4*)(&pbuf[wave][l16][s4 * 16 + quad * 4]) = w;
            }
        }

        // ---- strip B: QK^T (K dies here) ----
        floatx4 stB[4];
        __builtin_amdgcn_s_setprio(1);
#pragma unroll
        for (int s4 = 0; s4 < 4; ++s4) {
#pragma unroll
            for (int r = 0; r < 4; ++r) stB[s4][r] = 0.f;
            stB[s4] = __builtin_amdgcn_mfma_f32_16x16x32_f16(bK0[s4], aQB0, stB[s4], 0, 0, 0);
            stB[s4] = __builtin_amdgcn_mfma_f32_16x16x32_f16(bK1[s4], aQB1, stB[s4], 0, 0, 0);
        }
        __builtin_amdgcn_s_setprio(0);

        // ---- V fragments (allocator reuses K's registers) ----
        half8 bV0[4], bV1[4];
#pragma unroll
        for (int s4 = 0; s4 < 4; ++s4) {
            const _Float16* vp = Vb + (size_t)(s4 * 16 + l16) * TSEQ + kb + quad * 8;
            bV0[s4] = *(const half8*)(vp);
            bV1[s4] = *(const half8*)(vp + 32);
        }

        // ---- strip A: PV (pbuf read precedes B's pbuf overwrite) ----
        if (actA) {
            half8 aP0 = *(const half8*)(&pbuf[wave][l16][quad * 8]);
            half8 aP1 = *(const half8*)(&pbuf[wave][l16][32 + quad * 8]);
            __builtin_amdgcn_s_setprio(1);
#pragma unroll
            for (int s4 = 0; s4 < 4; ++s4) {
                accO[s4] = __builtin_amdgcn_mfma_f32_16x16x32_f16(aP0, bV0[s4], accO[s4], 0, 0, 0);
                accO[s4] = __builtin_amdgcn_mfma_f32_16x16x32_f16(aP1, bV1[s4], accO[s4], 0, 0, 0);
            }
            accL[0] = __builtin_amdgcn_mfma_f32_16x16x32_f16(aP0, ones, accL[0], 0, 0, 0);
            accL[0] = __builtin_amdgcn_mfma_f32_16x16x32_f16(aP1, ones, accL[0], 0, 0, 0);
            __builtin_amdgcn_s_setprio(0);
        }

        // ---- strip B: exp -> pbuf, PV ----
        {
            const int qrow = qB + l16;
#pragma unroll
            for (int s4 = 0; s4 < 4; ++s4) {
                half4 w;
#pragma unroll
                for (int r = 0; r < 4; ++r) {
                    float p = __expf(fminf(stB[s4][r], 18.f) - MBIAS);
                    if (j == jdB) {
                        const int kcol = kb + s4 * 16 + quad * 4 + r;
                        if (kcol > qrow) p = 0.f;
                    }
                    w[r] = (_Float16)p;
                }
                *(half4*)(&pbuf[wave][l16][s4 * 16 + quad * 4]) = w;
            }
            half8 aP0 = *(const half8*)(&pbuf[wave][l16][quad * 8]);
            half8 aP1 = *(const half8*)(&pbuf[wave][l16][32 + quad * 8]);
            __builtin_amdgcn_s_setprio(1);
#pragma unroll
            for (int s4 = 0; s4 < 4; ++s4) {
                accO[4 + s4] = __builtin_amdgcn_mfma_f32_16x16x32_f16(aP0, bV0[s4], accO[4 + s4], 0, 0, 0);
                accO[4 + s4] = __builtin_amdgcn_mfma_f32_16x16x32_f16(aP1, bV1[s4], accO[4 + s4], 0, 0, 0);
            }
            accL[1] = __builtin_amdgcn_mfma_f32_16x16x32_f16(aP0, ones, accL[1], 0, 0, 0);
            accL[1] = __builtin_amdgcn_mfma_f32_16x16x32_f16(aP1, ones, accL[1], 0, 0, 0);
            __builtin_amdgcn_s_setprio(0);
        }
    }

    // ---- merge the 4 k-phases (exact: fixed-bias softmax) ----
    if (h != 0) {
#pragma unroll
        for (int i = 0; i < 8; ++i) mbuf[h - 1][i][lane] = accO[i];
        mbuf[h - 1][8][lane] = accL[0];
        mbuf[h - 1][9][lane] = accL[1];
    }
    __syncthreads();
    if (h != 0) return;

#pragma unroll
    for (int m = 0; m < 3; ++m) {
#pragma unroll
        for (int i = 0; i < 8; ++i) {
            floatx4 t = mbuf[m][i][lane];
#pragma unroll
            for (int r = 0; r < 4; ++r) accO[i][r] += t[r];
        }
        floatx4 t8 = mbuf[m][8][lane];
        floatx4 t9 = mbuf[m][9][lane];
#pragma unroll
        for (int r = 0; r < 4; ++r) { accL[0][r] += t8[r]; accL[1][r] += t9[r]; }
    }

    // ---- epilogue (phase-0 wave writes both strips) ----
#pragma unroll
    for (int s = 0; s < 2; ++s) {
        const int qbase = (s == 0) ? qA : qB;
        float inv[4];
#pragma unroll
        for (int r = 0; r < 4; ++r) inv[r] = 1.f / accL[s][r];
#pragma unroll
        for (int s4 = 0; s4 < 4; ++s4) {
            const int dcol = s4 * 16 + l16;
#pragma unroll
            for (int r = 0; r < 4; ++r) {
                const int qr = qbase + quad * 4 + r;
                out[((size_t)(b0 + bl) * TSEQ + qr) * HD + dcol] =
                    accO[s * 4 + s4][r] * inv[r];
            }
        }
    }
}

// ---------------------------------------------------------------------------
extern "C" void kernel_launch(void* const* d_in, const int* in_sizes, int n_in,
                              void* d_out, int out_size, void* d_ws, size_t ws_size,
                              hipStream_t stream)
{
    char* ws = (char*)d_ws;
    _Float16* Wp = (_Float16*)ws;                           // 147456 B
    char* qkv_base = ws + 147456;

    const size_t per_b = (size_t)3 * TSEQ * HD * sizeof(_Float16);  // 196608 B
    size_t avail = (ws_size > (size_t)147456) ? ws_size - 147456 : per_b;
    int nbc = (int)(avail / per_b);
    if (nbc > NB) nbc = NB;
    if (nbc < 1)  nbc = 1;

    const size_t chunk_elems = (size_t)nbc * TSEQ * HD;
    _Float16* Qw  = (_Float16*)qkv_base;
    _Float16* Kw  = Qw + chunk_elems;
    _Float16* Vtw = Kw + chunk_elems;

    prep_w<<<dim3((3 * CDIM * HD + 255) / 256), dim3(256), 0, stream>>>(
        (const float*)d_in[1], (const float*)d_in[3], (const float*)d_in[5], Wp);

    for (int b0 = 0; b0 < NB; b0 += nbc) {
        const int nb = (NB - b0 < nbc) ? (NB - b0) : nbc;
        qkv_gemm<<<dim3(nb * 4), dim3(512), 0, stream>>>(
            (const float*)d_in[0], Wp, (const float*)d_in[2], (const float*)d_in[4],
            (const float*)d_in[6], Qw, Kw, Vtw, b0);
        attn_kernel<<<dim3(16, nb), dim3(256), 0, stream>>>(
            Qw, Kw, Vtw, (float*)d_out, b0);
    }
}